// Round 11
// baseline (39.259 us; speedup 1.0000x reference)
//
#include <hip/hip_runtime.h>

namespace {

constexpr int OUT_F = 11008;
constexpr int IN_F  = 4096;
constexpr int R4    = IN_F / 4;          // 1024 vec4 per row (x and qw)
constexpr int NLOAD = IN_F / (64 * 4);   // 16 int4 loads per lane per row

typedef int   int4v   __attribute__((ext_vector_type(4)));
typedef float float4v __attribute__((ext_vector_type(4)));

// Copy-kernel shape: one wave = one output row, load -> compute -> store ->
// exit. No LDS, no barriers, no loops over rows, no clamping. The HW
// dispatcher's block turnover provides the latency hiding (this is the m13
// 6.29 TB/s structure). x (64 KB) is L1/L2/LLC-hot — read directly.
__global__ __launch_bounds__(256) void qlinear_kernel(
    const float* __restrict__ x,       // [4, IN_F]
    const int*   __restrict__ qw,      // [OUT_F, IN_F]
    const float* __restrict__ scales,  // [OUT_F]
    const float* __restrict__ bias,    // [OUT_F]
    float*       __restrict__ out)     // [4, OUT_F]
{
    const int tid  = threadIdx.x;
    const int lane = tid & 63;
    const int row  = blockIdx.x * 4 + (tid >> 6);   // 0..11007 exactly

    const int4v*   qw4 = (const int4v*)qw;
    const float4v* xg  = (const float4v*)x;

    // Issue the whole row's 16 KB immediately: 16 KB outstanding per wave.
    int4v buf[NLOAD];
    const int4v* wp = qw4 + (size_t)row * R4;
#pragma unroll
    for (int i = 0; i < NLOAD; ++i)
        buf[i] = wp[i * 64 + lane];

    float acc[4] = {0.f, 0.f, 0.f, 0.f};
#pragma unroll
    for (int k = 0; k < NLOAD; ++k) {
        float4v xv[4];
#pragma unroll
        for (int b = 0; b < 4; ++b)
            xv[b] = xg[b * R4 + k * 64 + lane];   // L1/L2 hit (x is 64 KB)
        float4v wf;
        wf.x = (float)buf[k].x;
        wf.y = (float)buf[k].y;
        wf.z = (float)buf[k].z;
        wf.w = (float)buf[k].w;
#pragma unroll
        for (int b = 0; b < 4; ++b) {
            acc[b] += wf.x * xv[b].x;
            acc[b] += wf.y * xv[b].y;
            acc[b] += wf.z * xv[b].z;
            acc[b] += wf.w * xv[b].w;
        }
    }

    // Butterfly reduction across the 64 lanes.
#pragma unroll
    for (int b = 0; b < 4; ++b) {
#pragma unroll
        for (int m = 32; m >= 1; m >>= 1)
            acc[b] += __shfl_xor(acc[b], m, 64);
    }

    if (lane == 0) {
        const float sc = scales[row];
        const float bz = bias[row];
#pragma unroll
        for (int b = 0; b < 4; ++b)
            out[(size_t)b * OUT_F + row] = acc[b] * sc + bz;
    }
}

}  // namespace

extern "C" void kernel_launch(void* const* d_in, const int* in_sizes, int n_in,
                              void* d_out, int out_size, void* d_ws, size_t ws_size,
                              hipStream_t stream) {
    const float* x      = (const float*)d_in[0];
    const int*   qw     = (const int*)d_in[1];
    const float* scales = (const float*)d_in[2];
    const float* bias   = (const float*)d_in[3];
    float*       out    = (float*)d_out;

    qlinear_kernel<<<OUT_F / 4, 256, 0, stream>>>(x, qw, scales, bias, out);
}